// Round 1
// baseline (1123.453 us; speedup 1.0000x reference)
//
#include <hip/hip_runtime.h>
#include <hip/hip_bf16.h>

// GCN: h1 = relu(GCNConv(x,W1,b1)); h2 = relu(GCNConv(h1,W2,b2));
// g = mean_pool(h2,batch); out = relu(g@Wf1+bf1)@Wf2+bf2
// N=100000, E=1600000, G=256, IN=205, HID=128, FC=64, OUT=2

#define N_NODES 100000
#define N_EDGES 1600000
#define N_GRAPHS 256
#define IN_DIM 205
#define HID 128
#define FC_DIM 64
#define OUT_DIM 2

// ---------------- degree / CSR build ----------------

__global__ void k_count(const int* __restrict__ dst, int* __restrict__ cnt, int e) {
    int i = blockIdx.x * blockDim.x + threadIdx.x;
    if (i < e) atomicAdd(&cnt[dst[i]], 1);
}

__global__ void k_deg(const int* __restrict__ cnt, float* __restrict__ dinv,
                      float* __restrict__ selfc, int n) {
    int i = blockIdx.x * blockDim.x + threadIdx.x;
    if (i < n) {
        float deg = (float)cnt[i] + 1.0f;
        dinv[i]  = rsqrtf(deg);
        selfc[i] = 1.0f / deg;
    }
}

// exclusive scan of cnt[n] -> row[0..n-1], block sums -> bsum
__global__ __launch_bounds__(256) void k_scan1(const int* __restrict__ cnt,
                                               int* __restrict__ row,
                                               int* __restrict__ bsum, int n) {
    __shared__ int s[256];
    int t = threadIdx.x;
    int i = blockIdx.x * 256 + t;
    int v = (i < n) ? cnt[i] : 0;
    s[t] = v;
    __syncthreads();
    for (int off = 1; off < 256; off <<= 1) {
        int add = (t >= off) ? s[t - off] : 0;
        __syncthreads();
        s[t] += add;
        __syncthreads();
    }
    if (i < n) row[i] = s[t] - v;            // exclusive within block
    if (t == 255) bsum[blockIdx.x] = s[255]; // block total
}

__global__ __launch_bounds__(512) void k_scan2(int* __restrict__ bsum,
                                               int* __restrict__ boff, int nb) {
    __shared__ int s[512];
    int t = threadIdx.x;
    int v = (t < nb) ? bsum[t] : 0;
    s[t] = v;
    __syncthreads();
    for (int off = 1; off < 512; off <<= 1) {
        int add = (t >= off) ? s[t - off] : 0;
        __syncthreads();
        s[t] += add;
        __syncthreads();
    }
    if (t < nb) boff[t] = s[t] - v; // exclusive
}

__global__ void k_scan3(int* __restrict__ row, const int* __restrict__ boff,
                        int* __restrict__ cursor, int n, int e) {
    int i = blockIdx.x * blockDim.x + threadIdx.x;
    if (i < n) {
        int r = row[i] + boff[blockIdx.x * blockDim.x >> 8 ? 0 : 0]; // placeholder (fixed below)
        (void)r;
    }
}

// (clean version used instead of k_scan3 above)
__global__ void k_scan3b(int* __restrict__ row, const int* __restrict__ boff,
                         int* __restrict__ cursor, int n, int e) {
    int i = blockIdx.x * blockDim.x + threadIdx.x;
    if (i < n) {
        int r = row[i] + boff[i >> 8];
        row[i] = r;
        cursor[i] = r;
    }
    if (i == 0) row[n] = e;
}

__global__ void k_fill(const int* __restrict__ src, const int* __restrict__ dst,
                       int* __restrict__ cursor, int* __restrict__ col, int e) {
    int i = blockIdx.x * blockDim.x + threadIdx.x;
    if (i < e) {
        int d = dst[i];
        int pos = atomicAdd(&cursor[d], 1);
        col[pos] = src[i];
    }
}

// ---------------- GEMM: C[n][128] = A[n][K] @ W[K][128] ----------------
// BM=64, BN=128(full), BK=32; 256 threads; thread tile 4x8.

#define BM 64
#define BK 32

__global__ __launch_bounds__(256) void k_gemm(const float* __restrict__ A,
                                              const float* __restrict__ W,
                                              float* __restrict__ C, int n, int K) {
    __shared__ float As[BK][BM + 4]; // stride 68 (float4-aligned rows)
    __shared__ float Ws[BK][HID];
    int tid = threadIdx.x;
    int tx = tid & 15;  // col group: cols tx*8..+7
    int ty = tid >> 4;  // row group: rows ty*4..+3
    int rowBase = blockIdx.x * BM;

    float acc[4][8];
#pragma unroll
    for (int i = 0; i < 4; ++i)
#pragma unroll
        for (int j = 0; j < 8; ++j) acc[i][j] = 0.f;

    for (int k0 = 0; k0 < K; k0 += BK) {
        // A tile: 64 rows x 32 k. thread: row=tid/4, k=(tid%4)*8..+7
        {
            int r = tid >> 2;
            int kg = (tid & 3) * 8;
            int grow = rowBase + r;
#pragma unroll
            for (int u = 0; u < 8; ++u) {
                int kk = k0 + kg + u;
                float v = 0.f;
                if (grow < n && kk < K) v = A[(size_t)grow * K + kk];
                As[kg + u][r] = v;
            }
        }
        // W tile: 32 k x 128 cols. thread: k=tid/8, cols=(tid%8)*16..+15
        {
            int kk = tid >> 3;
            int cg = (tid & 7) * 16;
            int gk = k0 + kk;
#pragma unroll
            for (int u = 0; u < 4; ++u) {
                float4 v = make_float4(0.f, 0.f, 0.f, 0.f);
                if (gk < K) v = *(const float4*)&W[(size_t)gk * HID + cg + u * 4];
                *(float4*)&Ws[kk][cg + u * 4] = v;
            }
        }
        __syncthreads();
#pragma unroll
        for (int k = 0; k < BK; ++k) {
            float4 a = *(const float4*)&As[k][ty * 4];
            float4 w0 = *(const float4*)&Ws[k][tx * 8];
            float4 w1 = *(const float4*)&Ws[k][tx * 8 + 4];
            float av[4] = {a.x, a.y, a.z, a.w};
            float wv[8] = {w0.x, w0.y, w0.z, w0.w, w1.x, w1.y, w1.z, w1.w};
#pragma unroll
            for (int i = 0; i < 4; ++i)
#pragma unroll
                for (int j = 0; j < 8; ++j) acc[i][j] = fmaf(av[i], wv[j], acc[i][j]);
        }
        __syncthreads();
    }
    // store
#pragma unroll
    for (int i = 0; i < 4; ++i) {
        int grow = rowBase + ty * 4 + i;
        if (grow < n) {
            float4 o0 = make_float4(acc[i][0], acc[i][1], acc[i][2], acc[i][3]);
            float4 o1 = make_float4(acc[i][4], acc[i][5], acc[i][6], acc[i][7]);
            *(float4*)&C[(size_t)grow * HID + tx * 8] = o0;
            *(float4*)&C[(size_t)grow * HID + tx * 8 + 4] = o1;
        }
    }
}

// ---------------- aggregation: wave per dst node ----------------
// out[i] = relu( dinv[i]*sum_{e in CSR[i]} dinv[src]*h[src] + selfc[i]*h[i] + b )

__global__ __launch_bounds__(256) void k_agg(const float* __restrict__ h,
                                             const int* __restrict__ rowp,
                                             const int* __restrict__ col,
                                             const float* __restrict__ dinv,
                                             const float* __restrict__ selfc,
                                             const float* __restrict__ bias,
                                             float* __restrict__ out, int n) {
    int wid = (blockIdx.x * blockDim.x + threadIdx.x) >> 6;
    int lane = threadIdx.x & 63;
    if (wid >= n) return;
    int beg = rowp[wid];
    int end = rowp[wid + 1];
    float acc0 = 0.f, acc1 = 0.f;
    for (int e = beg; e < end; ++e) {
        int s = col[e];
        float w = dinv[s];
        const float* hs = h + (size_t)s * HID;
        acc0 = fmaf(w, hs[lane], acc0);
        acc1 = fmaf(w, hs[lane + 64], acc1);
    }
    const float* hv = h + (size_t)wid * HID;
    float di = dinv[wid], sc = selfc[wid];
    float o0 = fmaf(di, acc0, fmaf(sc, hv[lane], bias[lane]));
    float o1 = fmaf(di, acc1, fmaf(sc, hv[lane + 64], bias[lane + 64]));
    out[(size_t)wid * HID + lane] = fmaxf(o0, 0.f);
    out[(size_t)wid * HID + lane + 64] = fmaxf(o1, 0.f);
}

// ---------------- pooling ----------------

__global__ void k_pool_sum(const float* __restrict__ h, const int* __restrict__ batch,
                           float* __restrict__ sums, int n) {
    int i = blockIdx.x * blockDim.x + threadIdx.x;
    if (i < n * HID) {
        int v = i >> 7, f = i & 127;
        atomicAdd(&sums[(size_t)batch[v] * HID + f], h[i]);
    }
}

__global__ void k_pool_cnt(const int* __restrict__ batch, float* __restrict__ cnts, int n) {
    int i = blockIdx.x * blockDim.x + threadIdx.x;
    if (i < n) atomicAdd(&cnts[batch[i]], 1.0f);
}

// ---------------- head: mean -> FC1(relu) -> FC2 ----------------

__global__ __launch_bounds__(64) void k_head(const float* __restrict__ sums,
                                             const float* __restrict__ cnts,
                                             const float* __restrict__ Wf1,
                                             const float* __restrict__ bf1,
                                             const float* __restrict__ Wf2,
                                             const float* __restrict__ bf2,
                                             float* __restrict__ out) {
    int g = blockIdx.x;
    int t = threadIdx.x; // 64 threads
    __shared__ float m[HID];
    __shared__ float a[FC_DIM];
    float c = fmaxf(cnts[g], 1.0f);
    float inv = 1.0f / c;
    m[t] = sums[(size_t)g * HID + t] * inv;
    m[t + 64] = sums[(size_t)g * HID + t + 64] * inv;
    __syncthreads();
    float acc = bf1[t];
#pragma unroll 8
    for (int k = 0; k < HID; ++k) acc = fmaf(m[k], Wf1[k * FC_DIM + t], acc);
    a[t] = fmaxf(acc, 0.f);
    __syncthreads();
    if (t < OUT_DIM) {
        float o = bf2[t];
#pragma unroll 8
        for (int k = 0; k < FC_DIM; ++k) o = fmaf(a[k], Wf2[k * OUT_DIM + t], o);
        out[g * OUT_DIM + t] = o;
    }
}

// ---------------- launch ----------------

extern "C" void kernel_launch(void* const* d_in, const int* in_sizes, int n_in,
                              void* d_out, int out_size, void* d_ws, size_t ws_size,
                              hipStream_t stream) {
    const float* x = (const float*)d_in[0];
    const int* ei = (const int*)d_in[1]; // [2][E]
    const int* batch = (const int*)d_in[2];
    const float* W1 = (const float*)d_in[3];
    const float* b1 = (const float*)d_in[4];
    const float* W2 = (const float*)d_in[5];
    const float* b2 = (const float*)d_in[6];
    const float* Wf1 = (const float*)d_in[7];
    const float* bf1 = (const float*)d_in[8];
    const float* Wf2 = (const float*)d_in[9];
    const float* bf2 = (const float*)d_in[10];
    float* out = (float*)d_out;

    const int N = N_NODES, E = N_EDGES;
    const int* src = ei;
    const int* dst = ei + E;

    // ---- workspace carve-up ----
    char* ws = (char*)d_ws;
    size_t off = 0;
    auto carve = [&](size_t bytes) -> char* {
        char* p = ws + off;
        off += (bytes + 255) & ~(size_t)255;
        return p;
    };
    float* t0 = (float*)carve((size_t)N * HID * 4); // XW result
    float* t1 = (float*)carve((size_t)N * HID * 4); // agg result
    int* cnt = (int*)carve((size_t)N * 4);
    int* rowp = (int*)carve((size_t)(N + 1) * 4);
    int* cursor = (int*)carve((size_t)N * 4);
    float* dinv = (float*)carve((size_t)N * 4);
    float* selfc = (float*)carve((size_t)N * 4);
    int* col = (int*)carve((size_t)E * 4);
    int* bsum = (int*)carve(4096);
    int* boff = (int*)carve(4096);
    float* psum = (float*)carve((size_t)N_GRAPHS * HID * 4);
    float* pcnt = (float*)carve((size_t)N_GRAPHS * 4);
    (void)ws_size;

    // ---- zero what we accumulate into ----
    hipMemsetAsync(cnt, 0, (size_t)N * 4, stream);
    hipMemsetAsync(psum, 0, (size_t)N_GRAPHS * HID * 4, stream);
    hipMemsetAsync(pcnt, 0, (size_t)N_GRAPHS * 4, stream);

    const int TB = 256;
    int ebl = (E + TB - 1) / TB;
    int nbl = (N + TB - 1) / TB;

    // ---- degree + CSR ----
    k_count<<<ebl, TB, 0, stream>>>(dst, cnt, E);
    k_deg<<<nbl, TB, 0, stream>>>(cnt, dinv, selfc, N);
    int nscan = (N + 255) / 256; // 391 blocks
    k_scan1<<<nscan, 256, 0, stream>>>(cnt, rowp, bsum, N);
    k_scan2<<<1, 512, 0, stream>>>(bsum, boff, nscan);
    k_scan3b<<<nscan, 256, 0, stream>>>(rowp, boff, cursor, N, E);
    k_fill<<<ebl, TB, 0, stream>>>(src, dst, cursor, col, E);

    // ---- layer 1 ----
    int gblk = (N + BM - 1) / BM;
    k_gemm<<<gblk, 256, 0, stream>>>(x, W1, t0, N, IN_DIM);
    k_agg<<<(N * 64 + TB - 1) / TB, TB, 0, stream>>>(t0, rowp, col, dinv, selfc, b1, t1, N);

    // ---- layer 2 ----
    k_gemm<<<gblk, 256, 0, stream>>>(t1, W2, t0, N, HID);
    k_agg<<<(N * 64 + TB - 1) / TB, TB, 0, stream>>>(t0, rowp, col, dinv, selfc, b2, t1, N);

    // ---- pool + head ----
    k_pool_sum<<<((size_t)N * HID + TB - 1) / TB, TB, 0, stream>>>(t1, batch, psum, N);
    k_pool_cnt<<<nbl, TB, 0, stream>>>(batch, pcnt, N);
    k_head<<<N_GRAPHS, 64, 0, stream>>>(psum, pcnt, Wf1, bf1, Wf2, bf2, out);
}

// Round 3
// 885.032 us; speedup vs baseline: 1.2694x; 1.2694x over previous
//
#include <hip/hip_runtime.h>
#include <hip/hip_bf16.h>

// GCN: h1 = relu(GCNConv(x,W1,b1)); h2 = relu(GCNConv(h1,W2,b2));
// g = mean_pool(h2,batch); out = relu(g@Wf1+bf1)@Wf2+bf2
// N=100000, E=1600000, G=256, IN=205, HID=128, FC=64, OUT=2
//
// Algebra: agg[i] = dinv_i * ( sum_{e:dst=i} dinv_src*h_src ) + dinv_i^2*h_i + b
//        = dinv_i * ( sum hs_src + hs_i ) + b   with hs = dinv*h.
// So GEMM epilogue scales each row by dinv[row]; agg is a pure gather-sum.

#define N_NODES 100000
#define N_EDGES 1600000
#define N_GRAPHS 256
#define IN_DIM 205
#define HID 128
#define FC_DIM 64
#define OUT_DIM 2

// ---------------- degree / CSR build ----------------

__global__ void k_count(const int* __restrict__ dst, int* __restrict__ cnt, int e) {
    int i = blockIdx.x * blockDim.x + threadIdx.x;
    if (i < e) atomicAdd(&cnt[dst[i]], 1);
}

__global__ void k_deg(const int* __restrict__ cnt, float* __restrict__ dinv, int n) {
    int i = blockIdx.x * blockDim.x + threadIdx.x;
    if (i < n) {
        float deg = (float)cnt[i] + 1.0f;
        dinv[i] = rsqrtf(deg);
    }
}

// exclusive scan of cnt[n] -> row[0..n-1], block sums -> bsum
__global__ __launch_bounds__(256) void k_scan1(const int* __restrict__ cnt,
                                               int* __restrict__ row,
                                               int* __restrict__ bsum, int n) {
    __shared__ int s[256];
    int t = threadIdx.x;
    int i = blockIdx.x * 256 + t;
    int v = (i < n) ? cnt[i] : 0;
    s[t] = v;
    __syncthreads();
    for (int off = 1; off < 256; off <<= 1) {
        int add = (t >= off) ? s[t - off] : 0;
        __syncthreads();
        s[t] += add;
        __syncthreads();
    }
    if (i < n) row[i] = s[t] - v;            // exclusive within block
    if (t == 255) bsum[blockIdx.x] = s[255]; // block total
}

__global__ __launch_bounds__(512) void k_scan2(int* __restrict__ bsum,
                                               int* __restrict__ boff, int nb) {
    __shared__ int s[512];
    int t = threadIdx.x;
    int v = (t < nb) ? bsum[t] : 0;
    s[t] = v;
    __syncthreads();
    for (int off = 1; off < 512; off <<= 1) {
        int add = (t >= off) ? s[t - off] : 0;
        __syncthreads();
        s[t] += add;
        __syncthreads();
    }
    if (t < nb) boff[t] = s[t] - v; // exclusive
}

__global__ void k_scan3b(int* __restrict__ row, const int* __restrict__ boff,
                         int* __restrict__ cursor, int n, int e) {
    int i = blockIdx.x * blockDim.x + threadIdx.x;
    if (i < n) {
        int r = row[i] + boff[i >> 8];
        row[i] = r;
        cursor[i] = r;
    }
    if (i == 0) row[n] = e;
}

__global__ void k_fill(const int* __restrict__ src, const int* __restrict__ dst,
                       int* __restrict__ cursor, int* __restrict__ col, int e) {
    int i = blockIdx.x * blockDim.x + threadIdx.x;
    if (i < e) {
        int d = dst[i];
        int pos = atomicAdd(&cursor[d], 1);
        col[pos] = src[i];
    }
}

// ---------------- GEMM: C[r][128] = dinv[r] * (A[r][K] @ W[K][128]) ----------------
// BM=64, BN=128(full), BK=32; 256 threads; thread tile 4 rows x 8 cols.
// Col mapping per thread: {tx*4..+3, 64+tx*4..+3} -> Ws reads are 2-way-bank (free).

#define BM 64
#define BK 32

template <bool VEC4A>
__global__ __launch_bounds__(256) void k_gemm(const float* __restrict__ A,
                                              const float* __restrict__ W,
                                              const float* __restrict__ dinv,
                                              float* __restrict__ C, int n, int K) {
    __shared__ float As[BK][BM + 4]; // row stride 68 floats (16B-aligned)
    __shared__ float Ws[BK][HID];
    int tid = threadIdx.x;
    int tx = tid & 15;  // col group
    int ty = tid >> 4;  // row group: rows ty*4..+3
    int rowBase = blockIdx.x * BM;

    float acc[4][8];
#pragma unroll
    for (int i = 0; i < 4; ++i)
#pragma unroll
        for (int j = 0; j < 8; ++j) acc[i][j] = 0.f;

    for (int k0 = 0; k0 < K; k0 += BK) {
        // A tile: 64 rows x 32 k. thread: row=tid/4, k=(tid%4)*8..+7
        {
            int r = tid >> 2;
            int kg = (tid & 3) * 8;
            int grow = rowBase + r;
            if (VEC4A) {
                // K % BK == 0 and rows 16B-aligned
                float4 a0 = make_float4(0.f, 0.f, 0.f, 0.f), a1 = a0;
                if (grow < n) {
                    const float* ap = &A[(size_t)grow * K + k0 + kg];
                    a0 = *(const float4*)ap;
                    a1 = *(const float4*)(ap + 4);
                }
                As[kg + 0][r] = a0.x; As[kg + 1][r] = a0.y;
                As[kg + 2][r] = a0.z; As[kg + 3][r] = a0.w;
                As[kg + 4][r] = a1.x; As[kg + 5][r] = a1.y;
                As[kg + 6][r] = a1.z; As[kg + 7][r] = a1.w;
            } else {
#pragma unroll
                for (int u = 0; u < 8; ++u) {
                    int kk = k0 + kg + u;
                    float v = 0.f;
                    if (grow < n && kk < K) v = A[(size_t)grow * K + kk];
                    As[kg + u][r] = v;
                }
            }
        }
        // W tile: 32 k x 128 cols. thread: k=tid/8, cols=(tid%8)*16..+15
        {
            int kk = tid >> 3;
            int cg = (tid & 7) * 16;
            int gk = k0 + kk;
#pragma unroll
            for (int u = 0; u < 4; ++u) {
                float4 v = make_float4(0.f, 0.f, 0.f, 0.f);
                if (gk < K) v = *(const float4*)&W[(size_t)gk * HID + cg + u * 4];
                *(float4*)&Ws[kk][cg + u * 4] = v;
            }
        }
        __syncthreads();
#pragma unroll
        for (int k = 0; k < BK; ++k) {
            float4 a = *(const float4*)&As[k][ty * 4];
            float4 w0 = *(const float4*)&Ws[k][tx * 4];        // banks tx*4: 2-way, free
            float4 w1 = *(const float4*)&Ws[k][64 + tx * 4];
            float av[4] = {a.x, a.y, a.z, a.w};
            float wv[8] = {w0.x, w0.y, w0.z, w0.w, w1.x, w1.y, w1.z, w1.w};
#pragma unroll
            for (int i = 0; i < 4; ++i)
#pragma unroll
                for (int j = 0; j < 8; ++j) acc[i][j] = fmaf(av[i], wv[j], acc[i][j]);
        }
        __syncthreads();
    }
    // store: C[row] = dinv[row] * acc
#pragma unroll
    for (int i = 0; i < 4; ++i) {
        int grow = rowBase + ty * 4 + i;
        if (grow < n) {
            float d = dinv[grow];
            float4 o0 = make_float4(d * acc[i][0], d * acc[i][1], d * acc[i][2], d * acc[i][3]);
            float4 o1 = make_float4(d * acc[i][4], d * acc[i][5], d * acc[i][6], d * acc[i][7]);
            *(float4*)&C[(size_t)grow * HID + tx * 4] = o0;
            *(float4*)&C[(size_t)grow * HID + 64 + tx * 4] = o1;
        }
    }
}

// ---------------- aggregation: wave per dst node ----------------
// out[i] = relu( dinv[i]*(sum_{e in CSR[i]} hs[src] + hs[i]) + b )

__global__ __launch_bounds__(256) void k_agg(const float* __restrict__ hs,
                                             const int* __restrict__ rowp,
                                             const int* __restrict__ col,
                                             const float* __restrict__ dinv,
                                             const float* __restrict__ bias,
                                             float* __restrict__ out, int n) {
    int wid = (blockIdx.x * blockDim.x + threadIdx.x) >> 6;
    int lane = threadIdx.x & 63;
    if (wid >= n) return;
    int beg = rowp[wid];
    int end = rowp[wid + 1];
    const float2* h2 = (const float2*)hs; // row stride 64 float2
    float2 self = h2[(size_t)wid * 64 + lane];
    float ax = self.x, ay = self.y;
    for (int e = beg; e < end; ++e) {
        int s = col[e];
        float2 v = h2[(size_t)s * 64 + lane];
        ax += v.x;
        ay += v.y;
    }
    float2 bb = ((const float2*)bias)[lane];
    float di = dinv[wid];
    float ox = fmaf(di, ax, bb.x);
    float oy = fmaf(di, ay, bb.y);
    float2 o = make_float2(fmaxf(ox, 0.f), fmaxf(oy, 0.f));
    ((float2*)out)[(size_t)wid * 64 + lane] = o;
}

// ---------------- pooling (batch is SORTED -> no atomics) ----------------

// gstart[g] = lower_bound(batch, g); gstart[G] = n
__global__ __launch_bounds__(256) void k_bounds(const int* __restrict__ batch,
                                                int* __restrict__ gstart, int n) {
    int g = threadIdx.x; // 256 threads, 1 block
    int lo = 0, hi = n;
    while (lo < hi) {
        int mid = (lo + hi) >> 1;
        if (batch[mid] < g) lo = mid + 1; else hi = mid;
    }
    gstart[g] = lo;
    if (g == 0) gstart[N_GRAPHS] = n;
}

// one block per graph: mean over its contiguous node range
__global__ __launch_bounds__(256) void k_pool(const float* __restrict__ h,
                                              const int* __restrict__ gstart,
                                              float* __restrict__ gmean) {
    int g = blockIdx.x;
    int t = threadIdx.x;
    int f = t & 127;
    int half = t >> 7; // 0 or 1
    int s = gstart[g], e = gstart[g + 1];
    float acc = 0.f;
    for (int r = s + half; r < e; r += 2) acc += h[(size_t)r * HID + f];
    __shared__ float red[256];
    red[t] = acc;
    __syncthreads();
    if (t < 128) {
        int cnt = e - s;
        float m = (red[t] + red[t + 128]) / (float)max(cnt, 1);
        gmean[(size_t)g * HID + t] = m;
    }
}

// ---------------- head: FC1(relu) -> FC2 ----------------

__global__ __launch_bounds__(64) void k_head(const float* __restrict__ gmean,
                                             const float* __restrict__ Wf1,
                                             const float* __restrict__ bf1,
                                             const float* __restrict__ Wf2,
                                             const float* __restrict__ bf2,
                                             float* __restrict__ out) {
    int g = blockIdx.x;
    int t = threadIdx.x; // 64 threads
    __shared__ float m[HID];
    __shared__ float a[FC_DIM];
    m[t] = gmean[(size_t)g * HID + t];
    m[t + 64] = gmean[(size_t)g * HID + t + 64];
    __syncthreads();
    float acc = bf1[t];
#pragma unroll 8
    for (int k = 0; k < HID; ++k) acc = fmaf(m[k], Wf1[k * FC_DIM + t], acc);
    a[t] = fmaxf(acc, 0.f);
    __syncthreads();
    if (t < OUT_DIM) {
        float o = bf2[t];
#pragma unroll 8
        for (int k = 0; k < FC_DIM; ++k) o = fmaf(a[k], Wf2[k * OUT_DIM + t], o);
        out[g * OUT_DIM + t] = o;
    }
}

// ---------------- launch ----------------

extern "C" void kernel_launch(void* const* d_in, const int* in_sizes, int n_in,
                              void* d_out, int out_size, void* d_ws, size_t ws_size,
                              hipStream_t stream) {
    const float* x = (const float*)d_in[0];
    const int* ei = (const int*)d_in[1]; // [2][E]
    const int* batch = (const int*)d_in[2];
    const float* W1 = (const float*)d_in[3];
    const float* b1 = (const float*)d_in[4];
    const float* W2 = (const float*)d_in[5];
    const float* b2 = (const float*)d_in[6];
    const float* Wf1 = (const float*)d_in[7];
    const float* bf1 = (const float*)d_in[8];
    const float* Wf2 = (const float*)d_in[9];
    const float* bf2 = (const float*)d_in[10];
    float* out = (float*)d_out;

    const int N = N_NODES, E = N_EDGES;
    const int* src = ei;
    const int* dst = ei + E;

    // ---- workspace carve-up ----
    char* ws = (char*)d_ws;
    size_t off = 0;
    auto carve = [&](size_t bytes) -> char* {
        char* p = ws + off;
        off += (bytes + 255) & ~(size_t)255;
        return p;
    };
    float* t0 = (float*)carve((size_t)N * HID * 4); // hs (scaled XW)
    float* t1 = (float*)carve((size_t)N * HID * 4); // agg result
    int* cnt = (int*)carve((size_t)N * 4);
    int* rowp = (int*)carve((size_t)(N + 1) * 4);
    int* cursor = (int*)carve((size_t)N * 4);
    float* dinv = (float*)carve((size_t)N * 4);
    int* col = (int*)carve((size_t)E * 4);
    int* bsum = (int*)carve(4096);
    int* boff = (int*)carve(4096);
    int* gstart = (int*)carve((size_t)(N_GRAPHS + 1) * 4);
    float* gmean = (float*)carve((size_t)N_GRAPHS * HID * 4);
    (void)ws_size;

    // ---- zero what we accumulate into ----
    hipMemsetAsync(cnt, 0, (size_t)N * 4, stream);

    const int TB = 256;
    int ebl = (E + TB - 1) / TB;
    int nbl = (N + TB - 1) / TB;

    // ---- degree + CSR ----
    k_count<<<ebl, TB, 0, stream>>>(dst, cnt, E);
    k_deg<<<nbl, TB, 0, stream>>>(cnt, dinv, N);
    int nscan = (N + 255) / 256; // 391 blocks
    k_scan1<<<nscan, 256, 0, stream>>>(cnt, rowp, bsum, N);
    k_scan2<<<1, 512, 0, stream>>>(bsum, boff, nscan);
    k_scan3b<<<nscan, 256, 0, stream>>>(rowp, boff, cursor, N, E);
    k_fill<<<ebl, TB, 0, stream>>>(src, dst, cursor, col, E);

    // ---- layer 1 (K=205: scalar A loads) ----
    int gblk = (N + BM - 1) / BM;
    k_gemm<false><<<gblk, 256, 0, stream>>>(x, W1, dinv, t0, N, IN_DIM);
    k_agg<<<(N * 64 + TB - 1) / TB, TB, 0, stream>>>(t0, rowp, col, dinv, b1, t1, N);

    // ---- layer 2 (K=128: float4 A loads) ----
    k_gemm<true><<<gblk, 256, 0, stream>>>(t1, W2, dinv, t0, N, HID);
    k_agg<<<(N * 64 + TB - 1) / TB, TB, 0, stream>>>(t0, rowp, col, dinv, b2, t1, N);

    // ---- pool + head (no atomics: batch is sorted) ----
    k_bounds<<<1, 256, 0, stream>>>(batch, gstart, N);
    k_pool<<<N_GRAPHS, 256, 0, stream>>>(t1, gstart, gmean);
    k_head<<<N_GRAPHS, 64, 0, stream>>>(gmean, Wf1, bf1, Wf2, bf2, out);
}

// Round 4
// 839.301 us; speedup vs baseline: 1.3386x; 1.0545x over previous
//
#include <hip/hip_runtime.h>
#include <hip/hip_bf16.h>

// GCN: h1 = relu(GCNConv(x,W1,b1)); h2 = relu(GCNConv(h1,W2,b2));
// g = mean_pool(h2,batch); out = relu(g@Wf1+bf1)@Wf2+bf2
// N=100000, E=1600000, G=256, IN=205, HID=128, FC=64, OUT=2
//
// Algebra: agg[i] = dinv_i * ( sum_{e:dst=i} hs_src + hs_i ) + b, hs = dinv*(A@W).

#define N_NODES 100000
#define N_EDGES 1600000
#define N_GRAPHS 256
#define IN_DIM 205
#define HID 128
#define FC_DIM 64
#define OUT_DIM 2

// ---------------- degree / CSR build ----------------

__global__ void k_count(const int* __restrict__ dst, int* __restrict__ cnt, int e) {
    int i = blockIdx.x * blockDim.x + threadIdx.x;
    if (i < e) atomicAdd(&cnt[dst[i]], 1);
}

__global__ void k_deg(const int* __restrict__ cnt, float* __restrict__ dinv, int n) {
    int i = blockIdx.x * blockDim.x + threadIdx.x;
    if (i < n) {
        float deg = (float)cnt[i] + 1.0f;
        dinv[i] = rsqrtf(deg);
    }
}

// exclusive scan of cnt[n] -> row[0..n-1], block sums -> bsum
__global__ __launch_bounds__(256) void k_scan1(const int* __restrict__ cnt,
                                               int* __restrict__ row,
                                               int* __restrict__ bsum, int n) {
    __shared__ int s[256];
    int t = threadIdx.x;
    int i = blockIdx.x * 256 + t;
    int v = (i < n) ? cnt[i] : 0;
    s[t] = v;
    __syncthreads();
    for (int off = 1; off < 256; off <<= 1) {
        int add = (t >= off) ? s[t - off] : 0;
        __syncthreads();
        s[t] += add;
        __syncthreads();
    }
    if (i < n) row[i] = s[t] - v;            // exclusive within block
    if (t == 255) bsum[blockIdx.x] = s[255]; // block total
}

__global__ __launch_bounds__(512) void k_scan2(int* __restrict__ bsum,
                                               int* __restrict__ boff, int nb) {
    __shared__ int s[512];
    int t = threadIdx.x;
    int v = (t < nb) ? bsum[t] : 0;
    s[t] = v;
    __syncthreads();
    for (int off = 1; off < 512; off <<= 1) {
        int add = (t >= off) ? s[t - off] : 0;
        __syncthreads();
        s[t] += add;
        __syncthreads();
    }
    if (t < nb) boff[t] = s[t] - v; // exclusive
}

__global__ void k_scan3b(int* __restrict__ row, const int* __restrict__ boff,
                         int* __restrict__ cursor, int n, int e) {
    int i = blockIdx.x * blockDim.x + threadIdx.x;
    if (i < n) {
        int r = row[i] + boff[i >> 8];
        row[i] = r;
        cursor[i] = r;
    }
    if (i == 0) row[n] = e;
}

__global__ void k_fill(const int* __restrict__ src, const int* __restrict__ dst,
                       int* __restrict__ cursor, int* __restrict__ col, int e) {
    int i = blockIdx.x * blockDim.x + threadIdx.x;
    if (i < e) {
        int d = dst[i];
        int pos = atomicAdd(&cursor[d], 1);
        col[pos] = src[i];
    }
}

// ---------------- GEMM: C[r][128] = dinv[r] * (A[r][K] @ W[K][128]) ----------------
// BM=128, BN=128, BK=32; 256 threads (4 waves); thread tile 8 rows x 8 cols.
// Cols per thread: {tx*4..+3, 64+tx*4..+3}. Rows: ty*8..+7.

#define BM 128
#define BK 32

template <bool VEC4A>
__global__ __launch_bounds__(256) void k_gemm(const float* __restrict__ A,
                                              const float* __restrict__ W,
                                              const float* __restrict__ dinv,
                                              float* __restrict__ C, int n, int K) {
    __shared__ float As[BK][BM + 4]; // row stride 132 floats, 16B-aligned
    __shared__ float Ws[BK][HID];
    int tid = threadIdx.x;
    int tx = tid & 15;  // col group
    int ty = tid >> 4;  // row group: rows ty*8..+7
    int rowBase = blockIdx.x * BM;

    float acc[8][8];
#pragma unroll
    for (int i = 0; i < 8; ++i)
#pragma unroll
        for (int j = 0; j < 8; ++j) acc[i][j] = 0.f;

    for (int k0 = 0; k0 < K; k0 += BK) {
        // A tile: 128 rows x 32 k. thread: row=tid/2, k=(tid%2)*16 .. +15
        {
            int r = tid >> 1;
            int kg = (tid & 1) * 16;
            int grow = rowBase + r;
            if (VEC4A) {
                // K % BK == 0, rows 16B-aligned
                float4 a[4];
#pragma unroll
                for (int u = 0; u < 4; ++u) a[u] = make_float4(0.f, 0.f, 0.f, 0.f);
                if (grow < n) {
                    const float* ap = &A[(size_t)grow * K + k0 + kg];
#pragma unroll
                    for (int u = 0; u < 4; ++u) a[u] = *(const float4*)(ap + u * 4);
                }
#pragma unroll
                for (int u = 0; u < 4; ++u) {
                    As[kg + u * 4 + 0][r] = a[u].x;
                    As[kg + u * 4 + 1][r] = a[u].y;
                    As[kg + u * 4 + 2][r] = a[u].z;
                    As[kg + u * 4 + 3][r] = a[u].w;
                }
            } else {
#pragma unroll
                for (int u = 0; u < 16; ++u) {
                    int kk = k0 + kg + u;
                    float v = 0.f;
                    if (grow < n && kk < K) v = A[(size_t)grow * K + kk];
                    As[kg + u][r] = v;
                }
            }
        }
        // W tile: 32 k x 128 cols. thread: k=tid/8, cols=(tid%8)*16..+15
        {
            int kk = tid >> 3;
            int cg = (tid & 7) * 16;
            int gk = k0 + kk;
#pragma unroll
            for (int u = 0; u < 4; ++u) {
                float4 v = make_float4(0.f, 0.f, 0.f, 0.f);
                if (gk < K) v = *(const float4*)&W[(size_t)gk * HID + cg + u * 4];
                *(float4*)&Ws[kk][cg + u * 4] = v;
            }
        }
        __syncthreads();
#pragma unroll
        for (int k = 0; k < BK; ++k) {
            float4 a0 = *(const float4*)&As[k][ty * 8];
            float4 a1 = *(const float4*)&As[k][ty * 8 + 4];
            float4 w0 = *(const float4*)&Ws[k][tx * 4];
            float4 w1 = *(const float4*)&Ws[k][64 + tx * 4];
            float av[8] = {a0.x, a0.y, a0.z, a0.w, a1.x, a1.y, a1.z, a1.w};
            float wv[8] = {w0.x, w0.y, w0.z, w0.w, w1.x, w1.y, w1.z, w1.w};
#pragma unroll
            for (int i = 0; i < 8; ++i)
#pragma unroll
                for (int j = 0; j < 8; ++j) acc[i][j] = fmaf(av[i], wv[j], acc[i][j]);
        }
        __syncthreads();
    }
    // store: C[row] = dinv[row] * acc
#pragma unroll
    for (int i = 0; i < 8; ++i) {
        int grow = rowBase + ty * 8 + i;
        if (grow < n) {
            float d = dinv[grow];
            float4 o0 = make_float4(d * acc[i][0], d * acc[i][1], d * acc[i][2], d * acc[i][3]);
            float4 o1 = make_float4(d * acc[i][4], d * acc[i][5], d * acc[i][6], d * acc[i][7]);
            *(float4*)&C[(size_t)grow * HID + tx * 4] = o0;
            *(float4*)&C[(size_t)grow * HID + 64 + tx * 4] = o1;
        }
    }
}

// ---------------- aggregation: wave per dst node, x4 unrolled gather ----------------
// out[i] = relu( dinv[i]*(sum_{e in CSR[i]} hs[src] + hs[i]) + b )

__global__ __launch_bounds__(256) void k_agg(const float* __restrict__ hs,
                                             const int* __restrict__ rowp,
                                             const int* __restrict__ col,
                                             const float* __restrict__ dinv,
                                             const float* __restrict__ bias,
                                             float* __restrict__ out, int n) {
    int wid = (blockIdx.x * blockDim.x + threadIdx.x) >> 6;
    int lane = threadIdx.x & 63;
    if (wid >= n) return;
    int beg = rowp[wid];
    int end = rowp[wid + 1];
    const float2* h2 = (const float2*)hs; // row stride 64 float2
    float2 self = h2[(size_t)wid * 64 + lane];
    float ax = self.x, ay = self.y;
    int e = beg;
    // 4 independent row-gathers in flight per iteration (MLP for latency hiding)
    for (; e + 4 <= end; e += 4) {
        int s0 = col[e], s1 = col[e + 1], s2 = col[e + 2], s3 = col[e + 3];
        float2 v0 = h2[(size_t)s0 * 64 + lane];
        float2 v1 = h2[(size_t)s1 * 64 + lane];
        float2 v2 = h2[(size_t)s2 * 64 + lane];
        float2 v3 = h2[(size_t)s3 * 64 + lane];
        ax += (v0.x + v1.x) + (v2.x + v3.x);
        ay += (v0.y + v1.y) + (v2.y + v3.y);
    }
    for (; e < end; ++e) {
        int s = col[e];
        float2 v = h2[(size_t)s * 64 + lane];
        ax += v.x;
        ay += v.y;
    }
    float2 bb = ((const float2*)bias)[lane];
    float di = dinv[wid];
    float ox = fmaf(di, ax, bb.x);
    float oy = fmaf(di, ay, bb.y);
    float2 o = make_float2(fmaxf(ox, 0.f), fmaxf(oy, 0.f));
    ((float2*)out)[(size_t)wid * 64 + lane] = o;
}

// ---------------- pooling (batch is SORTED -> no atomics) ----------------

__global__ __launch_bounds__(256) void k_bounds(const int* __restrict__ batch,
                                                int* __restrict__ gstart, int n) {
    int g = threadIdx.x; // 256 threads, 1 block
    int lo = 0, hi = n;
    while (lo < hi) {
        int mid = (lo + hi) >> 1;
        if (batch[mid] < g) lo = mid + 1; else hi = mid;
    }
    gstart[g] = lo;
    if (g == 0) gstart[N_GRAPHS] = n;
}

__global__ __launch_bounds__(256) void k_pool(const float* __restrict__ h,
                                              const int* __restrict__ gstart,
                                              float* __restrict__ gmean) {
    int g = blockIdx.x;
    int t = threadIdx.x;
    int f = t & 127;
    int half = t >> 7; // 0 or 1
    int s = gstart[g], e = gstart[g + 1];
    float acc = 0.f;
    for (int r = s + half; r < e; r += 2) acc += h[(size_t)r * HID + f];
    __shared__ float red[256];
    red[t] = acc;
    __syncthreads();
    if (t < 128) {
        int cnt = e - s;
        float m = (red[t] + red[t + 128]) / (float)max(cnt, 1);
        gmean[(size_t)g * HID + t] = m;
    }
}

// ---------------- head: FC1(relu) -> FC2 ----------------

__global__ __launch_bounds__(64) void k_head(const float* __restrict__ gmean,
                                             const float* __restrict__ Wf1,
                                             const float* __restrict__ bf1,
                                             const float* __restrict__ Wf2,
                                             const float* __restrict__ bf2,
                                             float* __restrict__ out) {
    int g = blockIdx.x;
    int t = threadIdx.x; // 64 threads
    __shared__ float m[HID];
    __shared__ float a[FC_DIM];
    m[t] = gmean[(size_t)g * HID + t];
    m[t + 64] = gmean[(size_t)g * HID + t + 64];
    __syncthreads();
    float acc = bf1[t];
#pragma unroll 8
    for (int k = 0; k < HID; ++k) acc = fmaf(m[k], Wf1[k * FC_DIM + t], acc);
    a[t] = fmaxf(acc, 0.f);
    __syncthreads();
    if (t < OUT_DIM) {
        float o = bf2[t];
#pragma unroll 8
        for (int k = 0; k < FC_DIM; ++k) o = fmaf(a[k], Wf2[k * OUT_DIM + t], o);
        out[g * OUT_DIM + t] = o;
    }
}

// ---------------- launch ----------------

extern "C" void kernel_launch(void* const* d_in, const int* in_sizes, int n_in,
                              void* d_out, int out_size, void* d_ws, size_t ws_size,
                              hipStream_t stream) {
    const float* x = (const float*)d_in[0];
    const int* ei = (const int*)d_in[1]; // [2][E]
    const int* batch = (const int*)d_in[2];
    const float* W1 = (const float*)d_in[3];
    const float* b1 = (const float*)d_in[4];
    const float* W2 = (const float*)d_in[5];
    const float* b2 = (const float*)d_in[6];
    const float* Wf1 = (const float*)d_in[7];
    const float* bf1 = (const float*)d_in[8];
    const float* Wf2 = (const float*)d_in[9];
    const float* bf2 = (const float*)d_in[10];
    float* out = (float*)d_out;

    const int N = N_NODES, E = N_EDGES;
    const int* src = ei;
    const int* dst = ei + E;

    // ---- workspace carve-up ----
    char* ws = (char*)d_ws;
    size_t off = 0;
    auto carve = [&](size_t bytes) -> char* {
        char* p = ws + off;
        off += (bytes + 255) & ~(size_t)255;
        return p;
    };
    float* t0 = (float*)carve((size_t)N * HID * 4); // hs (scaled XW)
    float* t1 = (float*)carve((size_t)N * HID * 4); // agg result
    int* cnt = (int*)carve((size_t)N * 4);
    int* rowp = (int*)carve((size_t)(N + 1) * 4);
    int* cursor = (int*)carve((size_t)N * 4);
    float* dinv = (float*)carve((size_t)N * 4);
    int* col = (int*)carve((size_t)E * 4);
    int* bsum = (int*)carve(4096);
    int* boff = (int*)carve(4096);
    int* gstart = (int*)carve((size_t)(N_GRAPHS + 1) * 4);
    float* gmean = (float*)carve((size_t)N_GRAPHS * HID * 4);
    (void)ws_size;

    // ---- zero what we accumulate into ----
    hipMemsetAsync(cnt, 0, (size_t)N * 4, stream);

    const int TB = 256;
    int ebl = (E + TB - 1) / TB;
    int nbl = (N + TB - 1) / TB;

    // ---- degree + CSR ----
    k_count<<<ebl, TB, 0, stream>>>(dst, cnt, E);
    k_deg<<<nbl, TB, 0, stream>>>(cnt, dinv, N);
    int nscan = (N + 255) / 256; // 391 blocks
    k_scan1<<<nscan, 256, 0, stream>>>(cnt, rowp, bsum, N);
    k_scan2<<<1, 512, 0, stream>>>(bsum, boff, nscan);
    k_scan3b<<<nscan, 256, 0, stream>>>(rowp, boff, cursor, N, E);
    k_fill<<<ebl, TB, 0, stream>>>(src, dst, cursor, col, E);

    // ---- layer 1 (K=205: scalar A loads) ----
    int gblk = (N + BM - 1) / BM;
    k_gemm<false><<<gblk, 256, 0, stream>>>(x, W1, dinv, t0, N, IN_DIM);
    k_agg<<<(N * 64 + TB - 1) / TB, TB, 0, stream>>>(t0, rowp, col, dinv, b1, t1, N);

    // ---- layer 2 (K=128: float4 A loads) ----
    k_gemm<true><<<gblk, 256, 0, stream>>>(t1, W2, dinv, t0, N, HID);
    k_agg<<<(N * 64 + TB - 1) / TB, TB, 0, stream>>>(t0, rowp, col, dinv, b2, t1, N);

    // ---- pool + head (no atomics: batch is sorted) ----
    k_bounds<<<1, 256, 0, stream>>>(batch, gstart, N);
    k_pool<<<N_GRAPHS, 256, 0, stream>>>(t1, gstart, gmean);
    k_head<<<N_GRAPHS, 64, 0, stream>>>(gmean, Wf1, bf1, Wf2, bf2, out);
}

// Round 7
// 732.579 us; speedup vs baseline: 1.5336x; 1.1457x over previous
//
#include <hip/hip_runtime.h>
#include <hip/hip_bf16.h>

// GCN: h1 = relu(GCNConv(x,W1,b1)); h2 = relu(GCNConv(h1,W2,b2));
// g = mean_pool(h2,batch); out = relu(g@Wf1+bf1)@Wf2+bf2
// N=100000, E=1600000, G=256, IN=205, HID=128, FC=64, OUT=2
//
// agg[i] = dinv_i * ( sum_{e:dst=i} hs_src + hs_i ) + b, hs = dinv*(A@W).
// GEMM via split-precision bf16 MFMA: A=Ah+Al, W=Wh+Wl (bf16),
// C = AhWh + AhWl + AlWh (AlWl ~2^-18 dropped).

#define N_NODES 100000
#define N_EDGES 1600000
#define N_GRAPHS 256
#define IN_DIM 205
#define HID 128
#define FC_DIM 64
#define OUT_DIM 2
#define KPAD1 224  // 205 padded to multiple of 32

typedef float f32x4 __attribute__((ext_vector_type(4)));
typedef short s16x8 __attribute__((ext_vector_type(8)));

__device__ __forceinline__ ushort f2bf(float x) {
    uint u = __float_as_uint(x);
    u += 0x7fffu + ((u >> 16) & 1u);
    return (ushort)(u >> 16);
}
__device__ __forceinline__ float bf2f(ushort b) { return __uint_as_float((uint)b << 16); }

// ---------------- degree / CSR build ----------------

__global__ void k_count(const int* __restrict__ dst, int* __restrict__ cnt, int e) {
    int i = blockIdx.x * blockDim.x + threadIdx.x;
    if (i < e) atomicAdd(&cnt[dst[i]], 1);
}

__global__ void k_deg(const int* __restrict__ cnt, float* __restrict__ dinv, int n) {
    int i = blockIdx.x * blockDim.x + threadIdx.x;
    if (i < n) {
        float deg = (float)cnt[i] + 1.0f;
        dinv[i] = rsqrtf(deg);
    }
}

__global__ __launch_bounds__(256) void k_scan1(const int* __restrict__ cnt,
                                               int* __restrict__ row,
                                               int* __restrict__ bsum, int n) {
    __shared__ int s[256];
    int t = threadIdx.x;
    int i = blockIdx.x * 256 + t;
    int v = (i < n) ? cnt[i] : 0;
    s[t] = v;
    __syncthreads();
    for (int off = 1; off < 256; off <<= 1) {
        int add = (t >= off) ? s[t - off] : 0;
        __syncthreads();
        s[t] += add;
        __syncthreads();
    }
    if (i < n) row[i] = s[t] - v;
    if (t == 255) bsum[blockIdx.x] = s[255];
}

__global__ __launch_bounds__(512) void k_scan2(int* __restrict__ bsum,
                                               int* __restrict__ boff, int nb) {
    __shared__ int s[512];
    int t = threadIdx.x;
    int v = (t < nb) ? bsum[t] : 0;
    s[t] = v;
    __syncthreads();
    for (int off = 1; off < 512; off <<= 1) {
        int add = (t >= off) ? s[t - off] : 0;
        __syncthreads();
        s[t] += add;
        __syncthreads();
    }
    if (t < nb) boff[t] = s[t] - v;
}

__global__ void k_scan3b(int* __restrict__ row, const int* __restrict__ boff,
                         int* __restrict__ cursor, int n, int e) {
    int i = blockIdx.x * blockDim.x + threadIdx.x;
    if (i < n) {
        int r = row[i] + boff[i >> 8];
        row[i] = r;
        cursor[i] = r;
    }
    if (i == 0) row[n] = e;
}

__global__ void k_fill(const int* __restrict__ src, const int* __restrict__ dst,
                       int* __restrict__ cursor, int* __restrict__ col, int e) {
    int i = blockIdx.x * blockDim.x + threadIdx.x;
    if (i < e) {
        int d = dst[i];
        int pos = atomicAdd(&cursor[d], 1);
        col[pos] = src[i];
    }
}

// ---------------- W pre-split: W[K][128] f32 -> Wh/Wl [128][Kpad] bf16 (transposed) ----

__global__ __launch_bounds__(256) void k_splitW(const float* __restrict__ W,
                                                ushort* __restrict__ Wh,
                                                ushort* __restrict__ Wl,
                                                int K, int Kpad) {
    int col = blockIdx.x;  // 0..127
    int k = threadIdx.x;
    if (k >= Kpad) return;
    float a = (k < K) ? W[(size_t)k * HID + col] : 0.f;
    ushort h = f2bf(a);
    ushort l = f2bf(a - bf2f(h));
    Wh[(size_t)col * Kpad + k] = h;
    Wl[(size_t)col * Kpad + k] = l;
}

// ---------------- GEMM: C[r][128] = dinv[r]*(A[r][K] @ W[K][128]) via bf16 MFMA ----
// tile 128x128, BK=32, 256 threads = 4 waves (2x2); wave does 4x4 16x16 tiles.
// LDS bf16 [128][40] (pad 40 -> uniform banks). 3 MFMA terms per tile per k-step.

template <bool VEC4A>
__global__ __launch_bounds__(256) void k_gemm_mfma(const float* __restrict__ A,
                                                   const ushort* __restrict__ Wh,
                                                   const ushort* __restrict__ Wl,
                                                   const float* __restrict__ dinv,
                                                   float* __restrict__ C,
                                                   int n, int K, int Kpad) {
    __shared__ ushort Ah[128 * 40];
    __shared__ ushort Al[128 * 40];
    __shared__ ushort Bh[128 * 40];
    __shared__ ushort Bl[128 * 40];

    int tid = threadIdx.x;
    int lane = tid & 63;
    int wave = tid >> 6;      // 0..3
    int wy = wave >> 1;       // row half
    int wx = wave & 1;        // col half
    int r15 = lane & 15;
    int g = lane >> 4;        // k-group 0..3
    int rowBase = blockIdx.x * 128;

    f32x4 acc[4][4];
#pragma unroll
    for (int i = 0; i < 4; ++i)
#pragma unroll
        for (int j = 0; j < 4; ++j) acc[i][j] = (f32x4)(0.f);

    int srow = tid >> 1;      // staging row (A) / col (W): 0..127
    int khalf = tid & 1;      // k sub-half: 16*khalf

    for (int k0 = 0; k0 < Kpad; k0 += 32) {
        // ---- stage A: load 16 f32, split to bf16 hi/lo, pack, 4x b128 LDS stores ----
        float av[16];
        int grow = rowBase + srow;
        int kb = k0 + khalf * 16;
        if (VEC4A) {
            if (grow < n) {
                const float* ap = &A[(size_t)grow * K + kb];
#pragma unroll
                for (int u = 0; u < 4; ++u) {
                    float4 v = *(const float4*)(ap + 4 * u);
                    av[4 * u + 0] = v.x; av[4 * u + 1] = v.y;
                    av[4 * u + 2] = v.z; av[4 * u + 3] = v.w;
                }
            } else {
#pragma unroll
                for (int u = 0; u < 16; ++u) av[u] = 0.f;
            }
        } else {
#pragma unroll
            for (int u = 0; u < 16; ++u) {
                int kk = kb + u;
                av[u] = (grow < n && kk < K) ? A[(size_t)grow * K + kk] : 0.f;
            }
        }
        uint hp[8], lp[8];
#pragma unroll
        for (int u = 0; u < 8; ++u) {
            ushort h0 = f2bf(av[2 * u]), h1 = f2bf(av[2 * u + 1]);
            ushort l0 = f2bf(av[2 * u] - bf2f(h0));
            ushort l1 = f2bf(av[2 * u + 1] - bf2f(h1));
            hp[u] = (uint)h0 | ((uint)h1 << 16);
            lp[u] = (uint)l0 | ((uint)l1 << 16);
        }
        {
            int base = srow * 40 + khalf * 16; // ushort units; *2 bytes, 16B-aligned
            *(uint4*)&Ah[base]     = make_uint4(hp[0], hp[1], hp[2], hp[3]);
            *(uint4*)&Ah[base + 8] = make_uint4(hp[4], hp[5], hp[6], hp[7]);
            *(uint4*)&Al[base]     = make_uint4(lp[0], lp[1], lp[2], lp[3]);
            *(uint4*)&Al[base + 8] = make_uint4(lp[4], lp[5], lp[6], lp[7]);
        }
        // ---- stage W tiles (already bf16, transposed [col][Kpad]) ----
        {
            int col = srow;
            size_t gofs = (size_t)col * Kpad + k0 + khalf * 16;
            uint4 w0 = *(const uint4*)&Wh[gofs];
            uint4 w1 = *(const uint4*)&Wh[gofs + 8];
            uint4 x0 = *(const uint4*)&Wl[gofs];
            uint4 x1 = *(const uint4*)&Wl[gofs + 8];
            int wb = col * 40 + khalf * 16;
            *(uint4*)&Bh[wb]     = w0;
            *(uint4*)&Bh[wb + 8] = w1;
            *(uint4*)&Bl[wb]     = x0;
            *(uint4*)&Bl[wb + 8] = x1;
        }
        __syncthreads();
        // ---- fragments + MFMA ----
        s16x8 afh[4], afl[4];
#pragma unroll
        for (int tr = 0; tr < 4; ++tr) {
            int ai = (wy * 64 + tr * 16 + r15) * 40 + g * 8;
            afh[tr] = *(const s16x8*)&Ah[ai];
            afl[tr] = *(const s16x8*)&Al[ai];
        }
#pragma unroll
        for (int tc = 0; tc < 4; ++tc) {
            int bi = (wx * 64 + tc * 16 + r15) * 40 + g * 8;
            s16x8 bfh = *(const s16x8*)&Bh[bi];
            s16x8 bfl = *(const s16x8*)&Bl[bi];
#pragma unroll
            for (int tr = 0; tr < 4; ++tr) {
                acc[tr][tc] = __builtin_amdgcn_mfma_f32_16x16x32_bf16(afh[tr], bfh, acc[tr][tc], 0, 0, 0);
                acc[tr][tc] = __builtin_amdgcn_mfma_f32_16x16x32_bf16(afh[tr], bfl, acc[tr][tc], 0, 0, 0);
                acc[tr][tc] = __builtin_amdgcn_mfma_f32_16x16x32_bf16(afl[tr], bfh, acc[tr][tc], 0, 0, 0);
            }
        }
        __syncthreads();
    }
    // ---- epilogue: C[row] = dinv[row]*acc ----
#pragma unroll
    for (int tr = 0; tr < 4; ++tr) {
#pragma unroll
        for (int j = 0; j < 4; ++j) {
            int grow = rowBase + wy * 64 + tr * 16 + g * 4 + j;
            if (grow < n) {
                float d = dinv[grow];
#pragma unroll
                for (int tc = 0; tc < 4; ++tc) {
                    C[(size_t)grow * HID + wx * 64 + tc * 16 + r15] = d * acc[tr][tc][j];
                }
            }
        }
    }
}

// ---------------- aggregation: wave per dst node, x4 unrolled gather ----------------

__global__ __launch_bounds__(256) void k_agg(const float* __restrict__ hs,
                                             const int* __restrict__ rowp,
                                             const int* __restrict__ col,
                                             const float* __restrict__ dinv,
                                             const float* __restrict__ bias,
                                             float* __restrict__ out, int n) {
    int wid = (blockIdx.x * blockDim.x + threadIdx.x) >> 6;
    int lane = threadIdx.x & 63;
    if (wid >= n) return;
    int beg = rowp[wid];
    int end = rowp[wid + 1];
    const float2* h2 = (const float2*)hs;
    float2 self = h2[(size_t)wid * 64 + lane];
    float ax = self.x, ay = self.y;
    int e = beg;
    for (; e + 4 <= end; e += 4) {
        int s0 = col[e], s1 = col[e + 1], s2 = col[e + 2], s3 = col[e + 3];
        float2 v0 = h2[(size_t)s0 * 64 + lane];
        float2 v1 = h2[(size_t)s1 * 64 + lane];
        float2 v2 = h2[(size_t)s2 * 64 + lane];
        float2 v3 = h2[(size_t)s3 * 64 + lane];
        ax += (v0.x + v1.x) + (v2.x + v3.x);
        ay += (v0.y + v1.y) + (v2.y + v3.y);
    }
    for (; e < end; ++e) {
        int s = col[e];
        float2 v = h2[(size_t)s * 64 + lane];
        ax += v.x;
        ay += v.y;
    }
    float2 bb = ((const float2*)bias)[lane];
    float di = dinv[wid];
    float ox = fmaf(di, ax, bb.x);
    float oy = fmaf(di, ay, bb.y);
    float2 o = make_float2(fmaxf(ox, 0.f), fmaxf(oy, 0.f));
    ((float2*)out)[(size_t)wid * 64 + lane] = o;
}

// ---------------- pooling (batch sorted -> no atomics) ----------------

__global__ __launch_bounds__(256) void k_bounds(const int* __restrict__ batch,
                                                int* __restrict__ gstart, int n) {
    int g = threadIdx.x;
    int lo = 0, hi = n;
    while (lo < hi) {
        int mid = (lo + hi) >> 1;
        if (batch[mid] < g) lo = mid + 1; else hi = mid;
    }
    gstart[g] = lo;
    if (g == 0) gstart[N_GRAPHS] = n;
}

__global__ __launch_bounds__(256) void k_pool(const float* __restrict__ h,
                                              const int* __restrict__ gstart,
                                              float* __restrict__ gmean) {
    int g = blockIdx.x;
    int t = threadIdx.x;
    int f = t & 127;
    int half = t >> 7;
    int s = gstart[g], e = gstart[g + 1];
    float acc = 0.f;
    for (int r = s + half; r < e; r += 2) acc += h[(size_t)r * HID + f];
    __shared__ float red[256];
    red[t] = acc;
    __syncthreads();
    if (t < 128) {
        int cnt = e - s;
        float m = (red[t] + red[t + 128]) / (float)max(cnt, 1);
        gmean[(size_t)g * HID + t] = m;
    }
}

// ---------------- head: FC1(relu) -> FC2 ----------------

__global__ __launch_bounds__(64) void k_head(const float* __restrict__ gmean,
                                             const float* __restrict__ Wf1,
                                             const float* __restrict__ bf1,
                                             const float* __restrict__ Wf2,
                                             const float* __restrict__ bf2,
                                             float* __restrict__ out) {
    int g = blockIdx.x;
    int t = threadIdx.x;
    __shared__ float m[HID];
    __shared__ float a[FC_DIM];
    m[t] = gmean[(size_t)g * HID + t];
    m[t + 64] = gmean[(size_t)g * HID + t + 64];
    __syncthreads();
    float acc = bf1[t];
#pragma unroll 8
    for (int k = 0; k < HID; ++k) acc = fmaf(m[k], Wf1[k * FC_DIM + t], acc);
    a[t] = fmaxf(acc, 0.f);
    __syncthreads();
    if (t < OUT_DIM) {
        float o = bf2[t];
#pragma unroll 8
        for (int k = 0; k < FC_DIM; ++k) o = fmaf(a[k], Wf2[k * OUT_DIM + t], o);
        out[g * OUT_DIM + t] = o;
    }
}

// ---------------- launch ----------------

extern "C" void kernel_launch(void* const* d_in, const int* in_sizes, int n_in,
                              void* d_out, int out_size, void* d_ws, size_t ws_size,
                              hipStream_t stream) {
    const float* x = (const float*)d_in[0];
    const int* ei = (const int*)d_in[1];
    const int* batch = (const int*)d_in[2];
    const float* W1 = (const float*)d_in[3];
    const float* b1 = (const float*)d_in[4];
    const float* W2 = (const float*)d_in[5];
    const float* b2 = (const float*)d_in[6];
    const float* Wf1 = (const float*)d_in[7];
    const float* bf1 = (const float*)d_in[8];
    const float* Wf2 = (const float*)d_in[9];
    const float* bf2 = (const float*)d_in[10];
    float* out = (float*)d_out;

    const int N = N_NODES, E = N_EDGES;
    const int* src = ei;
    const int* dst = ei + E;

    char* ws = (char*)d_ws;
    size_t off = 0;
    auto carve = [&](size_t bytes) -> char* {
        char* p = ws + off;
        off += (bytes + 255) & ~(size_t)255;
        return p;
    };
    float* t0 = (float*)carve((size_t)N * HID * 4);
    float* t1 = (float*)carve((size_t)N * HID * 4);
    int* cnt = (int*)carve((size_t)N * 4);
    int* rowp = (int*)carve((size_t)(N + 1) * 4);
    int* cursor = (int*)carve((size_t)N * 4);
    float* dinv = (float*)carve((size_t)N * 4);
    int* col = (int*)carve((size_t)E * 4);
    int* bsum = (int*)carve(4096);
    int* boff = (int*)carve(4096);
    int* gstart = (int*)carve((size_t)(N_GRAPHS + 1) * 4);
    float* gmean = (float*)carve((size_t)N_GRAPHS * HID * 4);
    ushort* Wh1 = (ushort*)carve((size_t)HID * KPAD1 * 2);
    ushort* Wl1 = (ushort*)carve((size_t)HID * KPAD1 * 2);
    ushort* Wh2 = (ushort*)carve((size_t)HID * HID * 2);
    ushort* Wl2 = (ushort*)carve((size_t)HID * HID * 2);
    (void)ws_size;

    hipMemsetAsync(cnt, 0, (size_t)N * 4, stream);

    const int TB = 256;
    int ebl = (E + TB - 1) / TB;
    int nbl = (N + TB - 1) / TB;

    // weight pre-split (tiny)
    k_splitW<<<HID, 256, 0, stream>>>(W1, Wh1, Wl1, IN_DIM, KPAD1);
    k_splitW<<<HID, 256, 0, stream>>>(W2, Wh2, Wl2, HID, HID);

    // degree + CSR
    k_count<<<ebl, TB, 0, stream>>>(dst, cnt, E);
    k_deg<<<nbl, TB, 0, stream>>>(cnt, dinv, N);
    int nscan = (N + 255) / 256;
    k_scan1<<<nscan, 256, 0, stream>>>(cnt, rowp, bsum, N);
    k_scan2<<<1, 512, 0, stream>>>(bsum, boff, nscan);
    k_scan3b<<<nscan, 256, 0, stream>>>(rowp, boff, cursor, N, E);
    k_fill<<<ebl, TB, 0, stream>>>(src, dst, cursor, col, E);

    int gblk = (N + 127) / 128;
    // layer 1 (K=205, scalar A loads)
    k_gemm_mfma<false><<<gblk, 256, 0, stream>>>(x, Wh1, Wl1, dinv, t0, N, IN_DIM, KPAD1);
    k_agg<<<(N * 64 + TB - 1) / TB, TB, 0, stream>>>(t0, rowp, col, dinv, b1, t1, N);

    // layer 2 (K=128, float4 A loads)
    k_gemm_mfma<true><<<gblk, 256, 0, stream>>>(t1, Wh2, Wl2, dinv, t0, N, HID, HID);
    k_agg<<<(N * 64 + TB - 1) / TB, TB, 0, stream>>>(t0, rowp, col, dinv, b2, t1, N);

    // pool + head
    k_bounds<<<1, 256, 0, stream>>>(batch, gstart, N);
    k_pool<<<N_GRAPHS, 256, 0, stream>>>(t1, gstart, gmean);
    k_head<<<N_GRAPHS, 64, 0, stream>>>(gmean, Wf1, bf1, Wf2, bf2, out);
}